// Round 3
// baseline (1647.296 us; speedup 1.0000x reference)
//
#include <hip/hip_runtime.h>
#include <hip/hip_bf16.h>

#define TT    2048
#define BATCH 64
#define IDIM  128
#define HDIM  256
#define ODIM  512
#define M1    (BATCH * TT)   // 131072 rows

typedef __bf16 bf16x4 __attribute__((ext_vector_type(4)));
typedef __bf16 bf16x8 __attribute__((ext_vector_type(8)));
typedef float  f32x4  __attribute__((ext_vector_type(4)));
typedef float  f32x2  __attribute__((ext_vector_type(2)));

// ---------------------------------------------------------------------------
// GEMM (B-transposed weights): C[m][n] = sum_k A[m][k] * Bw[n][k] + bias[n]
// (unchanged — ~145 us combined, not the bottleneck)
// ---------------------------------------------------------------------------
template<int BM, int NW, int N, int K>
__global__ __launch_bounds__(NW * 64)
void gemm_bt(const float* __restrict__ A, const float* __restrict__ Bw,
             const float* __restrict__ bias, float* __restrict__ C)
{
    constexpr int BN = NW * 64;
    constexpr int BK = 32;
    constexpr int PK = BK + 8;
    constexpr int MF = BM / 16;
    __shared__ __bf16 As[BM][PK];
    __shared__ __bf16 Bs[BN][PK];

    const int tid  = threadIdx.x;
    const int lane = tid & 63;
    const int wave = tid >> 6;
    const int l15  = lane & 15;
    const int l4   = lane >> 4;
    const long mrow = (long)blockIdx.x * BM;

    f32x4 acc[MF][4];
#pragma unroll
    for (int i = 0; i < MF; ++i)
#pragma unroll
        for (int j = 0; j < 4; ++j) acc[i][j] = (f32x4){0.f, 0.f, 0.f, 0.f};

    constexpr int THR   = NW * 64;
    constexpr int A_IT  = (BM * BK) / (THR * 4);
    constexpr int B_IT  = (BN * BK) / (THR * 4);

    for (int k0 = 0; k0 < K; k0 += BK) {
#pragma unroll
        for (int it = 0; it < A_IT; ++it) {
            int e = tid * 4 + it * THR * 4;
            int r = e / BK, c = e % BK;
            float4 v = *(const float4*)(A + (mrow + r) * K + (k0 + c));
            bf16x4 p = {(__bf16)v.x, (__bf16)v.y, (__bf16)v.z, (__bf16)v.w};
            *(bf16x4*)&As[r][c] = p;
        }
#pragma unroll
        for (int it = 0; it < B_IT; ++it) {
            int e = tid * 4 + it * THR * 4;
            int r = e / BK, c = e % BK;
            float4 v = *(const float4*)(Bw + (long)r * K + (k0 + c));
            bf16x4 p = {(__bf16)v.x, (__bf16)v.y, (__bf16)v.z, (__bf16)v.w};
            *(bf16x4*)&Bs[r][c] = p;
        }
        __syncthreads();

        const int kk = l4 * 8;
        bf16x8 a[MF], b[4];
#pragma unroll
        for (int mf = 0; mf < MF; ++mf)
            a[mf] = *(const bf16x8*)&As[mf * 16 + l15][kk];
#pragma unroll
        for (int nf = 0; nf < 4; ++nf)
            b[nf] = *(const bf16x8*)&Bs[wave * 64 + nf * 16 + l15][kk];
#pragma unroll
        for (int mf = 0; mf < MF; ++mf)
#pragma unroll
            for (int nf = 0; nf < 4; ++nf)
                acc[mf][nf] = __builtin_amdgcn_mfma_f32_16x16x32_bf16(
                    a[mf], b[nf], acc[mf][nf], 0, 0, 0);
        __syncthreads();
    }

#pragma unroll
    for (int nf = 0; nf < 4; ++nf) {
        const int col = wave * 64 + nf * 16 + l15;
        const float bv = bias[col];
#pragma unroll
        for (int mf = 0; mf < MF; ++mf) {
#pragma unroll
            for (int j = 0; j < 4; ++j) {
                long row = mrow + mf * 16 + l4 * 4 + j;
                C[row * N + col] = acc[mf][nf][j] + bv;
            }
        }
    }
}

// ---------------------------------------------------------------------------
// Sequential scan, reduce-scatter version.
//   512 threads = 8 waves; lane = gg2(2b)*16 + kb(4b); wave*4+gg2 = g-group.
//   Thread owns outputs g0..g0+7 (G=8) over k in [kb*16, kb*16+16) (KB=16).
//   W slice 8x16 f32 in registers (f32x2 pairs -> v_pk_fma_f32).
//   h in LDS, double-buffered, padded word(k)=k+(k>>4)*4 -> 2-way max (free).
//   Per thread/step: 4 ds_read_b128, 64 pk_fma, 4-level shfl reduce-SCATTER
//   (each lane ends owning ONE output: one tanh, leak from register),
//   kb<8 lanes write h to LDS+global. One barrier per step.
// ---------------------------------------------------------------------------
__global__ __launch_bounds__(512, 2)
void rnn_scan(const float* __restrict__ xp, const float* __restrict__ h0,
              const float* __restrict__ Whh, float* __restrict__ h_all)
{
    __shared__ float hs[2][320];   // 256 + 4-per-16 pad words
    const int tid  = threadIdx.x;
    const int wave = tid >> 6;
    const int lane = tid & 63;
    const int gg2  = lane >> 4;          // [0,4)
    const int kb   = lane & 15;          // [0,16)
    const int g0   = wave * 32 + gg2 * 8;
    const int b    = blockIdx.x;
    // output this lane finalizes after the reduce-scatter:
    const int gfin = g0 + (((kb & 1) << 2) | (kb & 2) | ((kb >> 2) & 1));
    const int wIdx = gfin + ((gfin >> 4) << 2);   // padded LDS word for gfin

    // --- W registers: 8 outputs x 16 k as f32x2 pairs
    f32x2 W2[8][8];
#pragma unroll
    for (int gp = 0; gp < 8; ++gp) {
        const float* wr = Whh + (long)(g0 + gp) * HDIM + kb * 16;
#pragma unroll
        for (int c = 0; c < 4; ++c) {
            f32x4 v = *(const f32x4*)(wr + c * 4);
            W2[gp][2 * c]     = (f32x2){v[0], v[1]};
            W2[gp][2 * c + 1] = (f32x2){v[2], v[3]};
        }
    }

    // --- init h buffer 0 (padded) + per-thread persistent h[gfin]
    if (tid < HDIM) {
        float v = h0[(long)b * HDIM + tid];
        hs[0][tid + ((tid >> 4) << 2)] = v;
    }
    float hold = h0[(long)b * HDIM + gfin];
    __syncthreads();

    const long base = (long)b * TT * HDIM;
    const int  kb5  = kb * 5;            // f32x4 index of padded k-base (kb*20 words)

    float xq = xp[base + gfin];          // current step's input projection

    for (int t = 0; t < TT; ++t) {
        const f32x4* hp4 = (const f32x4*)hs[t & 1];
        f32x4 hv0 = hp4[kb5 + 0];
        f32x4 hv1 = hp4[kb5 + 1];
        f32x4 hv2 = hp4[kb5 + 2];
        f32x4 hv3 = hp4[kb5 + 3];

        // prefetch next step's xp scalar (hidden under FMA burst)
        float xq_n = xq;
        if (t + 1 < TT)
            xq_n = xp[base + (long)(t + 1) * HDIM + gfin];

        f32x2 hp[8];
        hp[0] = (f32x2){hv0[0], hv0[1]};  hp[1] = (f32x2){hv0[2], hv0[3]};
        hp[2] = (f32x2){hv1[0], hv1[1]};  hp[3] = (f32x2){hv1[2], hv1[3]};
        hp[4] = (f32x2){hv2[0], hv2[1]};  hp[5] = (f32x2){hv2[2], hv2[3]};
        hp[6] = (f32x2){hv3[0], hv3[1]};  hp[7] = (f32x2){hv3[2], hv3[3]};

        f32x2 acc[8];
#pragma unroll
        for (int gp = 0; gp < 8; ++gp) acc[gp] = (f32x2){0.f, 0.f};
#pragma unroll
        for (int j = 0; j < 8; ++j)
#pragma unroll
            for (int gp = 0; gp < 8; ++gp)
                acc[gp] = __builtin_elementwise_fma(W2[gp][j], hp[j], acc[gp]);

        float s0 = acc[0][0] + acc[0][1];
        float s1 = acc[1][0] + acc[1][1];
        float s2 = acc[2][0] + acc[2][1];
        float s3 = acc[3][0] + acc[3][1];
        float s4 = acc[4][0] + acc[4][1];
        float s5 = acc[5][0] + acc[5][1];
        float s6 = acc[6][0] + acc[6][1];
        float s7 = acc[7][0] + acc[7][1];

        // ---- reduce-scatter across the 16 kb lanes ----
        // L1 (xor 1): keep outputs {0..3} if bit0==0 else {4..7}
        const bool b0 = (kb & 1);
        float k0 = b0 ? s4 : s0, d0 = b0 ? s0 : s4;
        float k1 = b0 ? s5 : s1, d1 = b0 ? s1 : s5;
        float k2 = b0 ? s6 : s2, d2 = b0 ? s2 : s6;
        float k3 = b0 ? s7 : s3, d3 = b0 ? s3 : s7;
        float t0 = k0 + __shfl_xor(d0, 1);
        float t1 = k1 + __shfl_xor(d1, 1);
        float t2 = k2 + __shfl_xor(d2, 1);
        float t3 = k3 + __shfl_xor(d3, 1);
        // L2 (xor 2): keep {0,1} if bit1==0 else {2,3}
        const bool b1 = (kb & 2);
        float m0 = b1 ? t2 : t0, e0 = b1 ? t0 : t2;
        float m1 = b1 ? t3 : t1, e1 = b1 ? t1 : t3;
        float u0 = m0 + __shfl_xor(e0, 2);
        float u1 = m1 + __shfl_xor(e1, 2);
        // L3 (xor 4): keep {0} if bit2==0 else {1}
        const bool b2 = (kb & 4);
        float n0 = b2 ? u1 : u0, f0 = b2 ? u0 : u1;
        float v0 = n0 + __shfl_xor(f0, 4);
        // L4 (xor 8): duplicate pair sums -> both lanes hold full dot product
        v0 += __shfl_xor(v0, 8);

        // ---- finalize ONE output per lane ----
        float pre = xq + v0;
        float e   = __expf(2.f * pre);
        float th  = 1.f - 2.f * __builtin_amdgcn_rcpf(1.f + e);
        float hn  = 0.9f * hold + 0.1f * th;
        hold = hn;

        if (kb < 8) {
            hs[(t + 1) & 1][wIdx] = hn;
            h_all[base + (long)t * HDIM + gfin] = hn;
        }
        xq = xq_n;
        __syncthreads();   // single barrier per step (double-buffered h)
    }
}

// ---------------------------------------------------------------------------
extern "C" void kernel_launch(void* const* d_in, const int* in_sizes, int n_in,
                              void* d_out, int out_size, void* d_ws, size_t ws_size,
                              hipStream_t stream)
{
    const float* x   = (const float*)d_in[0];
    const float* h0  = (const float*)d_in[1];
    const float* Wxh = (const float*)d_in[2];
    const float* bxh = (const float*)d_in[3];
    const float* Whh = (const float*)d_in[4];
    const float* Why = (const float*)d_in[5];
    const float* bhy = (const float*)d_in[6];

    float* y     = (float*)d_out;                 // (M1, 512)
    float* h_all = y + (long)M1 * ODIM;           // (M1, 256)
    float* xp    = y;   // scratch: xp fits in y region; dead before K3

    gemm_bt<64, 4, HDIM, IDIM><<<M1 / 64, 4 * 64, 0, stream>>>(x, Wxh, bxh, xp);
    rnn_scan<<<BATCH, 512, 0, stream>>>(xp, h0, Whh, h_all);
    gemm_bt<64, 8, ODIM, HDIM><<<M1 / 64, 8 * 64, 0, stream>>>(h_all, Why, bhy, y);
}

// Round 4
// 1572.305 us; speedup vs baseline: 1.0477x; 1.0477x over previous
//
#include <hip/hip_runtime.h>
#include <hip/hip_bf16.h>

#define TT    2048
#define BATCH 64
#define IDIM  128
#define HDIM  256
#define ODIM  512
#define M1    (BATCH * TT)   // 131072 rows

typedef __bf16 bf16x4 __attribute__((ext_vector_type(4)));
typedef __bf16 bf16x8 __attribute__((ext_vector_type(8)));
typedef float  f32x4  __attribute__((ext_vector_type(4)));
typedef float  f32x2  __attribute__((ext_vector_type(2)));

// ---------------------------------------------------------------------------
// GEMM (B-transposed weights): C[m][n] = sum_k A[m][k] * Bw[n][k] + bias[n]
// (unchanged — not the bottleneck)
// ---------------------------------------------------------------------------
template<int BM, int NW, int N, int K>
__global__ __launch_bounds__(NW * 64)
void gemm_bt(const float* __restrict__ A, const float* __restrict__ Bw,
             const float* __restrict__ bias, float* __restrict__ C)
{
    constexpr int BN = NW * 64;
    constexpr int BK = 32;
    constexpr int PK = BK + 8;
    constexpr int MF = BM / 16;
    __shared__ __bf16 As[BM][PK];
    __shared__ __bf16 Bs[BN][PK];

    const int tid  = threadIdx.x;
    const int lane = tid & 63;
    const int wave = tid >> 6;
    const int l15  = lane & 15;
    const int l4   = lane >> 4;
    const long mrow = (long)blockIdx.x * BM;

    f32x4 acc[MF][4];
#pragma unroll
    for (int i = 0; i < MF; ++i)
#pragma unroll
        for (int j = 0; j < 4; ++j) acc[i][j] = (f32x4){0.f, 0.f, 0.f, 0.f};

    constexpr int THR   = NW * 64;
    constexpr int A_IT  = (BM * BK) / (THR * 4);
    constexpr int B_IT  = (BN * BK) / (THR * 4);

    for (int k0 = 0; k0 < K; k0 += BK) {
#pragma unroll
        for (int it = 0; it < A_IT; ++it) {
            int e = tid * 4 + it * THR * 4;
            int r = e / BK, c = e % BK;
            float4 v = *(const float4*)(A + (mrow + r) * K + (k0 + c));
            bf16x4 p = {(__bf16)v.x, (__bf16)v.y, (__bf16)v.z, (__bf16)v.w};
            *(bf16x4*)&As[r][c] = p;
        }
#pragma unroll
        for (int it = 0; it < B_IT; ++it) {
            int e = tid * 4 + it * THR * 4;
            int r = e / BK, c = e % BK;
            float4 v = *(const float4*)(Bw + (long)r * K + (k0 + c));
            bf16x4 p = {(__bf16)v.x, (__bf16)v.y, (__bf16)v.z, (__bf16)v.w};
            *(bf16x4*)&Bs[r][c] = p;
        }
        __syncthreads();

        const int kk = l4 * 8;
        bf16x8 a[MF], b[4];
#pragma unroll
        for (int mf = 0; mf < MF; ++mf)
            a[mf] = *(const bf16x8*)&As[mf * 16 + l15][kk];
#pragma unroll
        for (int nf = 0; nf < 4; ++nf)
            b[nf] = *(const bf16x8*)&Bs[wave * 64 + nf * 16 + l15][kk];
#pragma unroll
        for (int mf = 0; mf < MF; ++mf)
#pragma unroll
            for (int nf = 0; nf < 4; ++nf)
                acc[mf][nf] = __builtin_amdgcn_mfma_f32_16x16x32_bf16(
                    a[mf], b[nf], acc[mf][nf], 0, 0, 0);
        __syncthreads();
    }

#pragma unroll
    for (int nf = 0; nf < 4; ++nf) {
        const int col = wave * 64 + nf * 16 + l15;
        const float bv = bias[col];
#pragma unroll
        for (int mf = 0; mf < MF; ++mf) {
#pragma unroll
            for (int j = 0; j < 4; ++j) {
                long row = mrow + mf * 16 + l4 * 4 + j;
                C[row * N + col] = acc[mf][nf][j] + bv;
            }
        }
    }
}

// ---------------------------------------------------------------------------
// Sequential scan, reduce-scatter + RAW-BARRIER version.
//   Same decomposition as R3 (G=8 outputs x KB=16 k-lanes, W in registers,
//   h double-buffered in padded LDS, 4-level shfl reduce-scatter).
//   KEY CHANGE: __syncthreads() -> raw s_barrier with ONLY lgkmcnt(0)
//   (no vmcnt drain). xp global prefetch (depth 2) and h_all stores stay
//   in flight across barriers instead of serializing ~900cy HBM latency
//   into every step.
// ---------------------------------------------------------------------------
__global__ __launch_bounds__(512, 2)
void rnn_scan(const float* __restrict__ xp, const float* __restrict__ h0,
              const float* __restrict__ Whh, float* __restrict__ h_all)
{
    __shared__ float hs[2][320];   // 256 + 4-per-16 pad words
    const int tid  = threadIdx.x;
    const int wave = tid >> 6;
    const int lane = tid & 63;
    const int gg2  = lane >> 4;          // [0,4)
    const int kb   = lane & 15;          // [0,16)
    const int g0   = wave * 32 + gg2 * 8;
    const int b    = blockIdx.x;
    // output this lane finalizes after the reduce-scatter:
    const int gfin = g0 + (((kb & 1) << 2) | (kb & 2) | ((kb >> 2) & 1));
    const int wIdx = gfin + ((gfin >> 4) << 2);   // padded LDS word for gfin

    // --- W registers: 8 outputs x 16 k as f32x2 pairs
    f32x2 W2[8][8];
#pragma unroll
    for (int gp = 0; gp < 8; ++gp) {
        const float* wr = Whh + (long)(g0 + gp) * HDIM + kb * 16;
#pragma unroll
        for (int c = 0; c < 4; ++c) {
            f32x4 v = *(const f32x4*)(wr + c * 4);
            W2[gp][2 * c]     = (f32x2){v[0], v[1]};
            W2[gp][2 * c + 1] = (f32x2){v[2], v[3]};
        }
    }

    // --- init h buffer 0 (padded) + per-thread persistent h[gfin]
    if (tid < HDIM) {
        float v = h0[(long)b * HDIM + tid];
        hs[0][tid + ((tid >> 4) << 2)] = v;
    }
    float hold = h0[(long)b * HDIM + gfin];
    __syncthreads();   // one full barrier before the loop is fine

    const long base = (long)b * TT * HDIM;
    const int  kb5  = kb * 5;            // f32x4 index of padded k-base

    // xp prefetch, depth 2
    float xq  = xp[base + gfin];
    float xq1 = (TT > 1) ? xp[base + HDIM + gfin] : 0.f;

    for (int t = 0; t < TT; ++t) {
        const f32x4* hp4 = (const f32x4*)hs[t & 1];
        f32x4 hv0 = hp4[kb5 + 0];
        f32x4 hv1 = hp4[kb5 + 1];
        f32x4 hv2 = hp4[kb5 + 2];
        f32x4 hv3 = hp4[kb5 + 3];

        // prefetch xp for t+2 (clamped index, branchless) — stays in flight
        // across the raw barrier (no vmcnt drain)
        int tn = (t + 2 < TT) ? (t + 2) : (TT - 1);
        float xq2 = xp[base + (long)tn * HDIM + gfin];

        f32x2 hp[8];
        hp[0] = (f32x2){hv0[0], hv0[1]};  hp[1] = (f32x2){hv0[2], hv0[3]};
        hp[2] = (f32x2){hv1[0], hv1[1]};  hp[3] = (f32x2){hv1[2], hv1[3]};
        hp[4] = (f32x2){hv2[0], hv2[1]};  hp[5] = (f32x2){hv2[2], hv2[3]};
        hp[6] = (f32x2){hv3[0], hv3[1]};  hp[7] = (f32x2){hv3[2], hv3[3]};

        f32x2 acc[8];
#pragma unroll
        for (int gp = 0; gp < 8; ++gp) acc[gp] = (f32x2){0.f, 0.f};
#pragma unroll
        for (int j = 0; j < 8; ++j)
#pragma unroll
            for (int gp = 0; gp < 8; ++gp)
                acc[gp] = __builtin_elementwise_fma(W2[gp][j], hp[j], acc[gp]);

        float s0 = acc[0][0] + acc[0][1];
        float s1 = acc[1][0] + acc[1][1];
        float s2 = acc[2][0] + acc[2][1];
        float s3 = acc[3][0] + acc[3][1];
        float s4 = acc[4][0] + acc[4][1];
        float s5 = acc[5][0] + acc[5][1];
        float s6 = acc[6][0] + acc[6][1];
        float s7 = acc[7][0] + acc[7][1];

        // ---- reduce-scatter across the 16 kb lanes ----
        const bool b0 = (kb & 1);
        float k0 = b0 ? s4 : s0, d0 = b0 ? s0 : s4;
        float k1 = b0 ? s5 : s1, d1 = b0 ? s1 : s5;
        float k2 = b0 ? s6 : s2, d2 = b0 ? s2 : s6;
        float k3 = b0 ? s7 : s3, d3 = b0 ? s3 : s7;
        float t0 = k0 + __shfl_xor(d0, 1);
        float t1 = k1 + __shfl_xor(d1, 1);
        float t2 = k2 + __shfl_xor(d2, 1);
        float t3 = k3 + __shfl_xor(d3, 1);
        const bool b1 = (kb & 2);
        float m0 = b1 ? t2 : t0, e0 = b1 ? t0 : t2;
        float m1 = b1 ? t3 : t1, e1 = b1 ? t1 : t3;
        float u0 = m0 + __shfl_xor(e0, 2);
        float u1 = m1 + __shfl_xor(e1, 2);
        const bool b2 = (kb & 4);
        float n0 = b2 ? u1 : u0, f0 = b2 ? u0 : u1;
        float v0 = n0 + __shfl_xor(f0, 4);
        v0 += __shfl_xor(v0, 8);   // both dup lanes hold the full dot product

        // ---- finalize ONE output per lane ----
        float pre = xq + v0;
        float e   = __expf(2.f * pre);
        float th  = 1.f - 2.f * __builtin_amdgcn_rcpf(1.f + e);
        float hn  = 0.9f * hold + 0.1f * th;
        hold = hn;

        if (kb < 8) {
            hs[(t + 1) & 1][wIdx] = hn;
            h_all[base + (long)t * HDIM + gfin] = hn;   // store floats across barrier
        }
        xq = xq1; xq1 = xq2;

        // ---- raw barrier: LDS visibility only, NO vmcnt drain ----
        __builtin_amdgcn_sched_barrier(0);
        asm volatile("s_waitcnt lgkmcnt(0)" ::: "memory");
        __builtin_amdgcn_s_barrier();
        __builtin_amdgcn_sched_barrier(0);
    }
}

// ---------------------------------------------------------------------------
extern "C" void kernel_launch(void* const* d_in, const int* in_sizes, int n_in,
                              void* d_out, int out_size, void* d_ws, size_t ws_size,
                              hipStream_t stream)
{
    const float* x   = (const float*)d_in[0];
    const float* h0  = (const float*)d_in[1];
    const float* Wxh = (const float*)d_in[2];
    const float* bxh = (const float*)d_in[3];
    const float* Whh = (const float*)d_in[4];
    const float* Why = (const float*)d_in[5];
    const float* bhy = (const float*)d_in[6];

    float* y     = (float*)d_out;                 // (M1, 512)
    float* h_all = y + (long)M1 * ODIM;           // (M1, 256)
    float* xp    = y;   // scratch: xp fits in y region; dead before K3

    gemm_bt<64, 4, HDIM, IDIM><<<M1 / 64, 4 * 64, 0, stream>>>(x, Wxh, bxh, xp);
    rnn_scan<<<BATCH, 512, 0, stream>>>(xp, h0, Whh, h_all);
    gemm_bt<64, 8, ODIM, HDIM><<<M1 / 64, 8 * 64, 0, stream>>>(h_all, Why, bhy, y);
}

// Round 5
// 1194.299 us; speedup vs baseline: 1.3793x; 1.3165x over previous
//
#include <hip/hip_runtime.h>
#include <hip/hip_bf16.h>

#define TT    2048
#define BATCH 64
#define IDIM  128
#define HDIM  256
#define ODIM  512
#define M1    (BATCH * TT)   // 131072 rows

typedef __bf16 bf16x4 __attribute__((ext_vector_type(4)));
typedef __bf16 bf16x8 __attribute__((ext_vector_type(8)));
typedef float  f32x4  __attribute__((ext_vector_type(4)));
typedef float  f32x2  __attribute__((ext_vector_type(2)));
typedef _Float16 f16;
typedef _Float16 f16x2 __attribute__((ext_vector_type(2)));
typedef _Float16 f16x8 __attribute__((ext_vector_type(8)));

// DPP lane-permute (full-rate VALU, no LDS pipe).
// 0xB1 = quad_perm[1,0,3,2] (xor1); 0x4E = quad_perm[2,3,0,1] (xor2);
// 0x141 = row_half_mirror (xor7);   0x128 = row_ror:8 (xor8 within row16).
template<int CTRL>
__device__ __forceinline__ float dppmov(float v) {
    return __int_as_float(__builtin_amdgcn_update_dpp(
        __float_as_int(v), __float_as_int(v), CTRL, 0xF, 0xF, false));
}

// ---------------------------------------------------------------------------
// GEMM (B-transposed weights): C[m][n] = sum_k A[m][k]*Bw[n][k] + bias[n]
// (unchanged — not the bottleneck)
// ---------------------------------------------------------------------------
template<int BM, int NW, int N, int K>
__global__ __launch_bounds__(NW * 64)
void gemm_bt(const float* __restrict__ A, const float* __restrict__ Bw,
             const float* __restrict__ bias, float* __restrict__ C)
{
    constexpr int BN = NW * 64;
    constexpr int BK = 32;
    constexpr int PK = BK + 8;
    constexpr int MF = BM / 16;
    __shared__ __bf16 As[BM][PK];
    __shared__ __bf16 Bs[BN][PK];

    const int tid  = threadIdx.x;
    const int lane = tid & 63;
    const int wave = tid >> 6;
    const int l15  = lane & 15;
    const int l4   = lane >> 4;
    const long mrow = (long)blockIdx.x * BM;

    f32x4 acc[MF][4];
#pragma unroll
    for (int i = 0; i < MF; ++i)
#pragma unroll
        for (int j = 0; j < 4; ++j) acc[i][j] = (f32x4){0.f, 0.f, 0.f, 0.f};

    constexpr int THR   = NW * 64;
    constexpr int A_IT  = (BM * BK) / (THR * 4);
    constexpr int B_IT  = (BN * BK) / (THR * 4);

    for (int k0 = 0; k0 < K; k0 += BK) {
#pragma unroll
        for (int it = 0; it < A_IT; ++it) {
            int e = tid * 4 + it * THR * 4;
            int r = e / BK, c = e % BK;
            float4 v = *(const float4*)(A + (mrow + r) * K + (k0 + c));
            bf16x4 p = {(__bf16)v.x, (__bf16)v.y, (__bf16)v.z, (__bf16)v.w};
            *(bf16x4*)&As[r][c] = p;
        }
#pragma unroll
        for (int it = 0; it < B_IT; ++it) {
            int e = tid * 4 + it * THR * 4;
            int r = e / BK, c = e % BK;
            float4 v = *(const float4*)(Bw + (long)r * K + (k0 + c));
            bf16x4 p = {(__bf16)v.x, (__bf16)v.y, (__bf16)v.z, (__bf16)v.w};
            *(bf16x4*)&Bs[r][c] = p;
        }
        __syncthreads();

        const int kk = l4 * 8;
        bf16x8 a[MF], b[4];
#pragma unroll
        for (int mf = 0; mf < MF; ++mf)
            a[mf] = *(const bf16x8*)&As[mf * 16 + l15][kk];
#pragma unroll
        for (int nf = 0; nf < 4; ++nf)
            b[nf] = *(const bf16x8*)&Bs[wave * 64 + nf * 16 + l15][kk];
#pragma unroll
        for (int mf = 0; mf < MF; ++mf)
#pragma unroll
            for (int nf = 0; nf < 4; ++nf)
                acc[mf][nf] = __builtin_amdgcn_mfma_f32_16x16x32_bf16(
                    a[mf], b[nf], acc[mf][nf], 0, 0, 0);
        __syncthreads();
    }

#pragma unroll
    for (int nf = 0; nf < 4; ++nf) {
        const int col = wave * 64 + nf * 16 + l15;
        const float bv = bias[col];
#pragma unroll
        for (int mf = 0; mf < MF; ++mf) {
#pragma unroll
            for (int j = 0; j < 4; ++j) {
                long row = mrow + mf * 16 + l4 * 4 + j;
                C[row * N + col] = acc[mf][nf][j] + bv;
            }
        }
    }
}

// ---------------------------------------------------------------------------
// Sequential scan, f16-dot2 + DPP-butterfly version.
//   512 threads = 8 waves; lane = gg2(2b)*16 + kb(4b). Thread owns 8 outputs
//   (slot-permuted) x 16 k. W as f16x2 in regs; h in LDS as f16 (padded
//   16->24 per block), double-buffered. Per thread/step:
//     2 ds_read_b128, 64 v_dot2_f32_f16 (2 MAC/lane/cy -> 256cy/SIMD floor),
//     4-level DPP butterfly (masks 1,2,7,8 - pure VALU, zero LDS pipe),
//     1 tanh, b3=0 lanes write h->LDS, b3=1 lanes write h_all->global.
//   Raw s_barrier with lgkmcnt-only drain; xp prefetch depth 2.
//   Slot permutation: slot j = output g0 + (j ^ mask),
//   mask = ((b0^b2)<<2)|((b1^b2)<<1)|b2  (dual basis to masks 1,2,7;
//   invariant under 8) -> butterfly needs NO cndmask selection.
// ---------------------------------------------------------------------------
__global__ __launch_bounds__(512, 2)
void rnn_scan(const float* __restrict__ xp, const float* __restrict__ h0,
              const float* __restrict__ Whh, float* __restrict__ h_all)
{
    __shared__ f16 hs[2][16 * 24];   // 16 k-blocks x (16+8 pad) f16, dbuf
    const int tid  = threadIdx.x;
    const int wave = tid >> 6;
    const int lane = tid & 63;
    const int gg2  = lane >> 4;          // row within wave (DPP row = 16 lanes)
    const int kb   = lane & 15;          // k-block
    const int g0   = wave * 32 + gg2 * 8;
    const int b    = blockIdx.x;

    const int b0 = kb & 1, b1 = (kb >> 1) & 1, b2 = (kb >> 2) & 1, b3 = kb >> 3;
    const int mask = (((b0 ^ b2) << 2) | ((b1 ^ b2) << 1) | b2);
    const int gfin = g0 + mask;          // output this lane finalizes

    // --- W registers: slot j = row (g0 + (j^mask)), 16 k as f16x2
    f16x2 W[8][8];
#pragma unroll
    for (int j = 0; j < 8; ++j) {
        const float* wr = Whh + (long)(g0 + (j ^ mask)) * HDIM + kb * 16;
#pragma unroll
        for (int c = 0; c < 4; ++c) {
            f32x4 v = *(const f32x4*)(wr + 4 * c);
            W[j][2 * c]     = (f16x2){(f16)v[0], (f16)v[1]};
            W[j][2 * c + 1] = (f16x2){(f16)v[2], (f16)v[3]};
        }
    }

    // --- init h buffer 0 (f16, padded) + per-thread persistent h[gfin] (f32)
    if (tid < HDIM) {
        float v = h0[(long)b * HDIM + tid];
        hs[0][(tid >> 4) * 24 + (tid & 15)] = (f16)v;
    }
    float hold = h0[(long)b * HDIM + gfin];
    __syncthreads();

    const float* xq_p = xp + (long)b * TT * HDIM + gfin;
    float*       ha_p = h_all + (long)b * TT * HDIM + gfin;

    float xq  = xq_p[0];
    float xq1 = xq_p[HDIM];
    xq_p += 2 * HDIM;                    // now points at t+2

    const int rdoff = kb * 24;           // f16 index of this k-block (48B, 16B-aligned)
    const int wroff = (gfin >> 4) * 24 + (gfin & 15);

    for (int t = 0; t < TT; ++t) {
        const f16* hb = hs[t & 1];
        f16x8 hlo = *(const f16x8*)(hb + rdoff);
        f16x8 hhi = *(const f16x8*)(hb + rdoff + 8);

        // prefetch xp for t+2 (stays in flight across raw barrier).
        // Overruns by <=2 rows at the very end: still inside the y region.
        float xq2 = xq_p[0];
        xq_p += HDIM;

        f16x2 hp[8];
        hp[0] = (f16x2){hlo[0], hlo[1]}; hp[1] = (f16x2){hlo[2], hlo[3]};
        hp[2] = (f16x2){hlo[4], hlo[5]}; hp[3] = (f16x2){hlo[6], hlo[7]};
        hp[4] = (f16x2){hhi[0], hhi[1]}; hp[5] = (f16x2){hhi[2], hhi[3]};
        hp[6] = (f16x2){hhi[4], hhi[5]}; hp[7] = (f16x2){hhi[6], hhi[7]};

        float a0 = 0.f, a1 = 0.f, a2 = 0.f, a3 = 0.f;
        float a4 = 0.f, a5 = 0.f, a6 = 0.f, a7 = 0.f;
#pragma unroll
        for (int c = 0; c < 8; ++c) {
            a0 = __builtin_amdgcn_fdot2(W[0][c], hp[c], a0, false);
            a1 = __builtin_amdgcn_fdot2(W[1][c], hp[c], a1, false);
            a2 = __builtin_amdgcn_fdot2(W[2][c], hp[c], a2, false);
            a3 = __builtin_amdgcn_fdot2(W[3][c], hp[c], a3, false);
            a4 = __builtin_amdgcn_fdot2(W[4][c], hp[c], a4, false);
            a5 = __builtin_amdgcn_fdot2(W[5][c], hp[c], a5, false);
            a6 = __builtin_amdgcn_fdot2(W[6][c], hp[c], a6, false);
            a7 = __builtin_amdgcn_fdot2(W[7][c], hp[c], a7, false);
        }

        // ---- DPP butterfly reduce-scatter (masks 1,2,7,8) ----
        float t0 = a0 + dppmov<0xB1>(a4);    // xor1: + partner slot j+4
        float t1 = a1 + dppmov<0xB1>(a5);
        float t2 = a2 + dppmov<0xB1>(a6);
        float t3 = a3 + dppmov<0xB1>(a7);
        float u0 = t0 + dppmov<0x4E>(t2);    // xor2: + partner slot j+2
        float u1 = t1 + dppmov<0x4E>(t3);
        float v  = u0 + dppmov<0x141>(u1);   // xor7 (row_half_mirror): + slot 1
        v += dppmov<0x128>(v);               // xor8 (row_ror:8): dup-combine

        // ---- finalize ONE output per lane (dup on kb, kb^8) ----
        float pre = xq + v;
        float e   = __expf(2.f * pre);
        float th  = 1.f - 2.f * __builtin_amdgcn_rcpf(1.f + e);
        float hn  = 0.9f * hold + 0.1f * th;
        hold = hn;

        if (b3) {
            ha_p[0] = hn;                        // global (stays in flight)
        } else {
            hs[(t + 1) & 1][wroff] = (f16)hn;    // LDS for next step
        }
        ha_p += HDIM;
        xq = xq1; xq1 = xq2;

        // ---- raw barrier: LDS visibility only, NO vmcnt drain ----
        __builtin_amdgcn_sched_barrier(0);
        asm volatile("s_waitcnt lgkmcnt(0)" ::: "memory");
        __builtin_amdgcn_s_barrier();
        __builtin_amdgcn_sched_barrier(0);
    }
}

// ---------------------------------------------------------------------------
extern "C" void kernel_launch(void* const* d_in, const int* in_sizes, int n_in,
                              void* d_out, int out_size, void* d_ws, size_t ws_size,
                              hipStream_t stream)
{
    const float* x   = (const float*)d_in[0];
    const float* h0  = (const float*)d_in[1];
    const float* Wxh = (const float*)d_in[2];
    const float* bxh = (const float*)d_in[3];
    const float* Whh = (const float*)d_in[4];
    const float* Why = (const float*)d_in[5];
    const float* bhy = (const float*)d_in[6];

    float* y     = (float*)d_out;                 // (M1, 512)
    float* h_all = y + (long)M1 * ODIM;           // (M1, 256)
    float* xp    = y;   // scratch: xp fits in y region; dead before K3

    gemm_bt<64, 4, HDIM, IDIM><<<M1 / 64, 4 * 64, 0, stream>>>(x, Wxh, bxh, xp);
    rnn_scan<<<BATCH, 512, 0, stream>>>(xp, h0, Whh, h_all);
    gemm_bt<64, 8, ODIM, HDIM><<<M1 / 64, 8 * 64, 0, stream>>>(h_all, Why, bhy, y);
}